// Round 19
// baseline (514.111 us; speedup 1.0000x reference)
//
#include <hip/hip_runtime.h>

#define NCC 1024
#define MODIN 198
#define MODOUT 68
#define HMODL 128

typedef __attribute__((ext_vector_type(8))) short s8v;   // 8 bf16 = 4 VGPR
typedef __attribute__((ext_vector_type(4))) float f4v;   // MFMA acc
typedef unsigned short ushort_t;
typedef unsigned int uint_t;

#define OFF_SW1 0
#define OFF_SW2 32768
#define OFF_MW1 49152
#define OFF_MW2 65536
#define FEATS_BYTE_OFF 262144   // feats: 8192 cells x 132 f32

__device__ __forceinline__ float fast_tanh(float x) {
    const float e = __builtin_amdgcn_exp2f(x * 2.885390081777927f);   // e^{2x}
    const float r = __builtin_amdgcn_rcpf(e + 1.f);
    return fmaf(-2.f, r, 1.f);
}
__device__ __forceinline__ float fast_sigmoid(float x) {
    const float e = __builtin_amdgcn_exp2f(x * -1.4426950408889634f);
    return __builtin_amdgcn_rcpf(e + 1.f);
}
__device__ __forceinline__ ushort_t f2bf(float x) {   // RNE f32->bf16 (scalar path)
    uint_t u = __builtin_bit_cast(uint_t, x);
    u += 0x7FFFu + ((u >> 16) & 1u);
    return (ushort_t)(u >> 16);
}
__device__ __forceinline__ uint_t pk2(float a, float b) {   // HW pack: 1 instr, RNE
    uint_t r;
    asm("v_cvt_pk_bf16_f32 %0, %1, %2" : "=v"(r) : "v"(a), "v"(b));
    return r;
}
// XOR swizzle on LDS byte offsets (16B granule)
#define SWZ(byteoff, row) ((byteoff) ^ (((row) & 7) << 4))

// ---------------------------------------------------------------------------
// Kernel 0: weights -> bf16 once per launch
// ---------------------------------------------------------------------------
__global__ __launch_bounds__(256)
void mg_cvtw(const float* __restrict__ sw1, const float* __restrict__ sw2,
             const float* __restrict__ mw1, const float* __restrict__ mw2,
             ushort_t* __restrict__ o) {
    const int i = blockIdx.x * 256 + threadIdx.x;   // grid 320 -> 81920 exact
    float v;
    if (i < 32768)      v = sw1[i];
    else if (i < 49152) v = sw2[i - 32768];
    else if (i < 65536) v = mw1[i - 49152];
    else                v = mw2[i - 65536];
    o[i] = f2bf(v);
}

// ---------------------------------------------------------------------------
// Kernel 0b: inject[b,c,o] -> head of each out_h tile (read by P1)
// ---------------------------------------------------------------------------
__global__ __launch_bounds__(256, 4)
void mg_inject(const float* __restrict__ xp, const float* __restrict__ iw,
               const float* __restrict__ ibias, const int* __restrict__ c2g,
               float* __restrict__ injb) {
    const int c = blockIdx.x, t = threadIdx.x;
    const int g = c2g[c];
    __shared__ float s_x[8][64];
    for (int idx = t; idx < 512; idx += 256)
        s_x[idx >> 6][idx & 63] = xp[(size_t)(idx >> 6) * (NCC * 64) + c * 64 + (idx & 63)];
    __syncthreads();
    const float* wrow = iw + (size_t)g * 16384 + t * 64;
    float a0 = 0.f, a1 = 0.f, a2 = 0.f, a3 = 0.f, a4 = 0.f, a5 = 0.f, a6 = 0.f, a7 = 0.f;
    #pragma unroll
    for (int i = 0; i < 64; i += 4) {
        const float4 w4 = *(const float4*)(wrow + i);
        const float4 x0 = *(const float4*)&s_x[0][i];
        const float4 x1 = *(const float4*)&s_x[1][i];
        const float4 x2 = *(const float4*)&s_x[2][i];
        const float4 x3 = *(const float4*)&s_x[3][i];
        const float4 x4 = *(const float4*)&s_x[4][i];
        const float4 x5 = *(const float4*)&s_x[5][i];
        const float4 x6 = *(const float4*)&s_x[6][i];
        const float4 x7 = *(const float4*)&s_x[7][i];
        a0 = fmaf(w4.x, x0.x, a0); a0 = fmaf(w4.y, x0.y, a0); a0 = fmaf(w4.z, x0.z, a0); a0 = fmaf(w4.w, x0.w, a0);
        a1 = fmaf(w4.x, x1.x, a1); a1 = fmaf(w4.y, x1.y, a1); a1 = fmaf(w4.z, x1.z, a1); a1 = fmaf(w4.w, x1.w, a1);
        a2 = fmaf(w4.x, x2.x, a2); a2 = fmaf(w4.y, x2.y, a2); a2 = fmaf(w4.z, x2.z, a2); a2 = fmaf(w4.w, x2.w, a2);
        a3 = fmaf(w4.x, x3.x, a3); a3 = fmaf(w4.y, x3.y, a3); a3 = fmaf(w4.z, x3.z, a3); a3 = fmaf(w4.w, x3.w, a3);
        a4 = fmaf(w4.x, x4.x, a4); a4 = fmaf(w4.y, x4.y, a4); a4 = fmaf(w4.z, x4.z, a4); a4 = fmaf(w4.w, x4.w, a4);
        a5 = fmaf(w4.x, x5.x, a5); a5 = fmaf(w4.y, x5.y, a5); a5 = fmaf(w4.z, x5.z, a5); a5 = fmaf(w4.w, x5.w, a5);
        a6 = fmaf(w4.x, x6.x, a6); a6 = fmaf(w4.y, x6.y, a6); a6 = fmaf(w4.z, x6.z, a6); a6 = fmaf(w4.w, x6.w, a6);
        a7 = fmaf(w4.x, x7.x, a7); a7 = fmaf(w4.y, x7.y, a7); a7 = fmaf(w4.z, x7.z, a7); a7 = fmaf(w4.w, x7.w, a7);
    }
    const float bv = ibias[g * 256 + t];
    const float acc[8] = {a0, a1, a2, a3, a4, a5, a6, a7};
    #pragma unroll
    for (int b = 0; b < 8; b++)
        injb[((size_t)b * NCC + c) * 4096 + t] = acc[b] + bv;
}

// ---------------------------------------------------------------------------
// Kernel 1: per (b, cell) block; 512 threads = 8 waves; full sHid [64][256],
// operand-swapped MFMAs, cvt_pk, cross-barrier prefetch, 1:2 read:MFMA in L1.
// Round-19: L2 phases re-decomposed (wcg = w&1 -> 2 weight frags; rq = w>>1
// -> 1 data tile) so L2's data reads also feed 2 MFMAs each.
// ---------------------------------------------------------------------------
__global__ __launch_bounds__(512, 4)
void mg_cell_kernel(
    const float* __restrict__ hp,   const float* __restrict__ msgp,
    const float* __restrict__ Wp,   const float* __restrict__ decayp,
    const float* __restrict__ bglp, const float* __restrict__ nidp,
    const float* __restrict__ sb1,  const float* __restrict__ sgs1,
    const float* __restrict__ sgb1, const float* __restrict__ sb2,
    const float* __restrict__ sgs2, const float* __restrict__ sgb2,
    const float* __restrict__ mb1,  const float* __restrict__ mgs1,
    const float* __restrict__ mgb1, const float* __restrict__ mb2,
    const float* __restrict__ mgs2, const float* __restrict__ mgb2,
    const int*   __restrict__ c2g,  const ushort_t* __restrict__ wb,
    float* __restrict__ out_read, float* __restrict__ out_h,
    float* __restrict__ out_msg,  float* __restrict__ wsf)
{
    const int t  = threadIdx.x;
    const int bc = blockIdx.x;
    const int b  = bc >> 10, c = bc & 1023;
    const int gh = c >> 5, gwc = c & 31;
    const int lane = t & 63, w = t >> 6;
    const int cl = lane & 15, q = lane >> 4;
    const int g  = c2g[c];
    const size_t tile = (size_t)bc * 4096;

    __shared__ ushort_t sHid[16384];   // [64][256] bf16 32KB; first 16KB overlays sW|sMsgT
    __shared__ ushort_t sIn[8192];     // [64][128] bf16: [received/h_new | h]
    __shared__ float s_scr[512];       // border [0:256); later h-parts[4][64] @0, m-parts[4][64] @256
    __shared__ float s_dec[64];
    __shared__ float s_wsum[8];
    __shared__ float s_dsum;

    ushort_t* sW    = sHid;            // [64][64], row stride 128B
    ushort_t* sMsgT = sHid + 4096;     // [64 d][64 m]

    // ================= P0: staging + border + decay =================
    {   // W -> sW bf16 (+ sum|W|): n = t>>3, 8 cols each
        const int n = t >> 3, m0 = (t & 7) * 8;
        const float* src = Wp + tile + n * 64 + m0;
        const float4 v0 = *(const float4*)(src);
        const float4 v1 = *(const float4*)(src + 4);
        float wsum = fabsf(v0.x) + fabsf(v0.y) + fabsf(v0.z) + fabsf(v0.w)
                   + fabsf(v1.x) + fabsf(v1.y) + fabsf(v1.z) + fabsf(v1.w);
        *(uint_t*)((char*)sW + SWZ(n * 128 + (m0 + 0) * 2, n)) = pk2(v0.x, v0.y);
        *(uint_t*)((char*)sW + SWZ(n * 128 + (m0 + 2) * 2, n)) = pk2(v0.z, v0.w);
        *(uint_t*)((char*)sW + SWZ(n * 128 + (m0 + 4) * 2, n)) = pk2(v1.x, v1.y);
        *(uint_t*)((char*)sW + SWZ(n * 128 + (m0 + 6) * 2, n)) = pk2(v1.z, v1.w);
        #pragma unroll
        for (int off = 32; off > 0; off >>= 1) wsum += __shfl_down(wsum, off);
        if (lane == 0) s_wsum[w] = wsum;
    }
    #pragma unroll
    for (int i = 0; i < 2; i++) {   // msg^T -> sMsgT bf16
        const int m = (t >> 4) + i * 32, d0 = (t & 15) * 4;
        const float4 v = *(const float4*)(msgp + tile + (size_t)m * 64 + d0);
        *(ushort_t*)((char*)sMsgT + SWZ((d0 + 0) * 128 + m * 2, d0 + 0)) = f2bf(v.x);
        *(ushort_t*)((char*)sMsgT + SWZ((d0 + 1) * 128 + m * 2, d0 + 1)) = f2bf(v.y);
        *(ushort_t*)((char*)sMsgT + SWZ((d0 + 2) * 128 + m * 2, d0 + 2)) = f2bf(v.z);
        *(ushort_t*)((char*)sMsgT + SWZ((d0 + 3) * 128 + m * 2, d0 + 3)) = f2bf(v.w);
    }
    #pragma unroll
    for (int i = 0; i < 2; i++) {   // h -> sIn[:,64:128] bf16
        const int n = (t >> 4) + i * 32, d0 = (t & 15) * 4;
        const float4 v = *(const float4*)(hp + tile + (size_t)n * 64 + d0);
        *(uint_t*)((char*)sIn + SWZ(n * 256 + (64 + d0) * 2, n))     = pk2(v.x, v.y);
        *(uint_t*)((char*)sIn + SWZ(n * 256 + (64 + d0 + 2) * 2, n)) = pk2(v.z, v.w);
    }
    if (t < 256) {   // gated border incoming: wave p = w (0..3)
        const int p = w, dd = lane;
        int ok, nc2, qq;
        if      (p == 0) { ok = (gh > 0);   nc2 = c - 32; qq = 1; }
        else if (p == 1) { ok = (gh < 31);  nc2 = c + 32; qq = 0; }
        else if (p == 2) { ok = (gwc > 0);  nc2 = c - 1;  qq = 3; }
        else             { ok = (gwc < 31); nc2 = c + 1;  qq = 2; }
        float v = 0.f;
        if (ok) v = msgp[((size_t)b * NCC + nc2) * 4096 + (8 + qq) * 64 + dd];
        s_scr[p * 64 + dd] = fast_sigmoid(bglp[(size_t)bc * 4 + p]) * v;
    }
    if (w == 4) {   // decay sigmoid table + logit sum
        const float dl = decayp[(size_t)bc * 64 + lane];
        s_dec[lane] = fast_sigmoid(dl);
        float v = dl;
        #pragma unroll
        for (int off = 32; off > 0; off >>= 1) v += __shfl_down(v, off);
        if (lane == 0) s_dsum = v;
    }
    __syncthreads();   // B1

    const f4v fzero = {0.f, 0.f, 0.f, 0.f};
    const int d0 = 16 * (w & 3) + q * 4;   // P1 epilogue cols
    const int dA = 16 * (w & 3) + cl;      // P1 weight-row index
    const int rh = w >> 2;                 // P1 row-half
    // L2-phase decomposition: 2 weight frags x 1 data tile per wave
    const int wcg = w & 1, rq = w >> 1;
    const int dL0 = 32 * wcg + cl, dL1 = dL0 + 16;   // L2 weight rows
    const int cA  = 32 * wcg + q * 4, cB = cA + 16;  // L2 output col-quads
    const int nL  = rq * 16 + cl;                    // L2 output row
    const ushort_t* wb1 = wb + OFF_SW1;
    const ushort_t* wb2 = wb + OFF_SW2;
    const ushort_t* wm1 = wb + OFF_MW1;
    const ushort_t* wm2 = wb + OFF_MW2;

    s8v awP0, awP1;   // cross-barrier first-fragment prefetch pair

    // ========== P1: received^ = mfma(msgT, W) + inject + border -> sIn[:,0:64] ==========
    {
        f4v wm[2] = {fzero, fzero};
        __builtin_amdgcn_s_setprio(1);
        #pragma unroll
        for (int ks = 0; ks < 2; ks++) {
            const int k0 = ks * 32 + q * 8;
            const s8v am = *(const s8v*)((const char*)sMsgT + SWZ(dA * 128 + k0 * 2, dA));
            #pragma unroll
            for (int nt = 0; nt < 2; nt++) {
                const int ar = (rh * 2 + nt) * 16 + cl;
                const s8v bw = *(const s8v*)((const char*)sW + SWZ(ar * 128 + k0 * 2, ar));
                wm[nt] = __builtin_amdgcn_mfma_f32_16x16x32_bf16(am, bw, wm[nt], 0, 0, 0);
            }
        }
        __builtin_amdgcn_s_setprio(0);
        // PREFETCH: state L1 ks=0 frags (ct=0,1); drained by B2
        awP0 = *(const s8v*)(wb1 + (size_t)(32 * w + cl) * 128 + q * 8);
        awP1 = *(const s8v*)(wb1 + (size_t)(32 * w + 16 + cl) * 128 + q * 8);
        #pragma unroll
        for (int nt = 0; nt < 2; nt++) {
            const int n = (rh * 2 + nt) * 16 + cl;
            float v0 = wm[nt][0], v1 = wm[nt][1], v2 = wm[nt][2], v3 = wm[nt][3];
            if (n < 4) {
                const float4 inj = *(const float4*)(out_h + tile + (size_t)n * 64 + d0);
                v0 += inj.x; v1 += inj.y; v2 += inj.z; v3 += inj.w;
            } else if (n >= 8 && n < 12) {
                const float4 bin = *(const float4*)&s_scr[(n - 8) * 64 + d0];
                v0 += bin.x; v1 += bin.y; v2 += bin.z; v3 += bin.w;
            }
            uint2 pkd; pkd.x = pk2(v0, v1); pkd.y = pk2(v2, v3);
            *(uint2*)((char*)sIn + SWZ(n * 256 + d0 * 2, n)) = pkd;
        }
    }
    __syncthreads();   // B2 (sW/sMsgT reads done -> sHid full overlay safe)

    // ===== state L1: K=128, wave w owns cols [32w, 32w+32); 1:2 read:MFMA =====
    {
        f4v acc[2][4];
        #pragma unroll
        for (int i = 0; i < 2; i++)
            #pragma unroll
            for (int j = 0; j < 4; j++) acc[i][j] = fzero;
        __builtin_amdgcn_s_setprio(1);
        #pragma unroll
        for (int ks = 0; ks < 4; ks++) {
            const int k0 = ks * 32 + q * 8;
            const s8v aw0 = (ks == 0) ? awP0
                : *(const s8v*)(wb1 + (size_t)(32 * w + cl) * 128 + k0);
            const s8v aw1 = (ks == 0) ? awP1
                : *(const s8v*)(wb1 + (size_t)(32 * w + 16 + cl) * 128 + k0);
            #pragma unroll
            for (int rt = 0; rt < 4; rt++) {
                const int ar = rt * 16 + cl;
                const s8v bi = *(const s8v*)((const char*)sIn + SWZ(ar * 256 + k0 * 2, ar));
                acc[0][rt] = __builtin_amdgcn_mfma_f32_16x16x32_bf16(aw0, bi, acc[0][rt], 0, 0, 0);
                acc[1][rt] = __builtin_amdgcn_mfma_f32_16x16x32_bf16(aw1, bi, acc[1][rt], 0, 0, 0);
            }
        }
        __builtin_amdgcn_s_setprio(0);
        // PREFETCH: state L2 ks=0 frags (both weight rows)
        awP0 = *(const s8v*)(wb2 + (size_t)dL0 * 256 + q * 8);
        awP1 = *(const s8v*)(wb2 + (size_t)dL1 * 256 + q * 8);
        #pragma unroll
        for (int ct = 0; ct < 2; ct++) {
            const int hc0 = 32 * w + ct * 16 + q * 4;
            const float4 b1 = *(const float4*)&sb1[hc0];
            const float4 g1 = *(const float4*)&sgs1[g * 256 + hc0];
            const float4 o1 = *(const float4*)&sgb1[g * 256 + hc0];
            #pragma unroll
            for (int rt = 0; rt < 4; rt++) {
                const int n = rt * 16 + cl;
                const float t0 = fast_tanh(fmaf(acc[ct][rt][0] + b1.x, g1.x, o1.x));
                const float t1 = fast_tanh(fmaf(acc[ct][rt][1] + b1.y, g1.y, o1.y));
                const float t2 = fast_tanh(fmaf(acc[ct][rt][2] + b1.z, g1.z, o1.z));
                const float t3 = fast_tanh(fmaf(acc[ct][rt][3] + b1.w, g1.w, o1.w));
                uint2 pkd; pkd.x = pk2(t0, t1); pkd.y = pk2(t2, t3);
                *(uint2*)((char*)sHid + SWZ(n * 512 + hc0 * 2, n)) = pkd;
            }
        }
    }
    __syncthreads();   // B3: full hid visible

    // ===== state L2: K=256, 2 weight frags x 1 data tile; 8 reads / 16 MFMA =====
    {
        f4v a2[2][2];
        a2[0][0] = fzero; a2[0][1] = fzero; a2[1][0] = fzero; a2[1][1] = fzero;
        __builtin_amdgcn_s_setprio(1);
        #pragma unroll
        for (int ks = 0; ks < 8; ks++) {
            const int k0 = ks * 32 + q * 8;
            const s8v aw0 = (ks == 0) ? awP0 : *(const s8v*)(wb2 + (size_t)dL0 * 256 + k0);
            const s8v aw1 = (ks == 0) ? awP1 : *(const s8v*)(wb2 + (size_t)dL1 * 256 + k0);
            const int ar = rq * 16 + cl;
            const s8v bh = *(const s8v*)((const char*)sHid + SWZ(ar * 512 + k0 * 2, ar));
            a2[0][ks & 1] = __builtin_amdgcn_mfma_f32_16x16x32_bf16(aw0, bh, a2[0][ks & 1], 0, 0, 0);
            a2[1][ks & 1] = __builtin_amdgcn_mfma_f32_16x16x32_bf16(aw1, bh, a2[1][ks & 1], 0, 0, 0);
        }
        __builtin_amdgcn_s_setprio(0);
        // PREFETCH: msg L1 ks=0 frags (ct=0,1)
        awP0 = *(const s8v*)(wm1 + (size_t)(32 * w + cl) * 64 + q * 8);
        awP1 = *(const s8v*)(wm1 + (size_t)(32 * w + 16 + cl) * 64 + q * 8);
        // epilogue: cand -> h_new for row nL, col-quads cA and cB
        const float dec = s_dec[nL];
        const float4 b2A = *(const float4*)&sb2[cA];
        const float4 g2A = *(const float4*)&sgs2[g * 64 + cA];
        const float4 o2A = *(const float4*)&sgb2[g * 64 + cA];
        const float4 b2B = *(const float4*)&sb2[cB];
        const float4 g2B = *(const float4*)&sgs2[g * 64 + cB];
        const float4 o2B = *(const float4*)&sgb2[g * 64 + cB];
        const uint2 huA = *(const uint2*)((const char*)sIn + SWZ(nL * 256 + (64 + cA) * 2, nL));
        const uint2 huB = *(const uint2*)((const char*)sIn + SWZ(nL * 256 + (64 + cB) * 2, nL));
        float4 hnA, hnB;
        {
            const float c0 = fast_tanh(fmaf(a2[0][0][0] + a2[0][1][0] + b2A.x, g2A.x, o2A.x));
            const float c1 = fast_tanh(fmaf(a2[0][0][1] + a2[0][1][1] + b2A.y, g2A.y, o2A.y));
            const float c2 = fast_tanh(fmaf(a2[0][0][2] + a2[0][1][2] + b2A.z, g2A.z, o2A.z));
            const float c3 = fast_tanh(fmaf(a2[0][0][3] + a2[0][1][3] + b2A.w, g2A.w, o2A.w));
            hnA.x = fmaf(dec, __builtin_bit_cast(float, (uint_t)(huA.x << 16)) - c0, c0);
            hnA.y = fmaf(dec, __builtin_bit_cast(float, huA.x & 0xFFFF0000u) - c1, c1);
            hnA.z = fmaf(dec, __builtin_bit_cast(float, (uint_t)(huA.y << 16)) - c2, c2);
            hnA.w = fmaf(dec, __builtin_bit_cast(float, huA.y & 0xFFFF0000u) - c3, c3);
            const float d0_ = fast_tanh(fmaf(a2[1][0][0] + a2[1][1][0] + b2B.x, g2B.x, o2B.x));
            const float d1_ = fast_tanh(fmaf(a2[1][0][1] + a2[1][1][1] + b2B.y, g2B.y, o2B.y));
            const float d2_ = fast_tanh(fmaf(a2[1][0][2] + a2[1][1][2] + b2B.z, g2B.z, o2B.z));
            const float d3_ = fast_tanh(fmaf(a2[1][0][3] + a2[1][1][3] + b2B.w, g2B.w, o2B.w));
            hnB.x = fmaf(dec, __builtin_bit_cast(float, (uint_t)(huB.x << 16)) - d0_, d0_);
            hnB.y = fmaf(dec, __builtin_bit_cast(float, huB.x & 0xFFFF0000u) - d1_, d1_);
            hnB.z = fmaf(dec, __builtin_bit_cast(float, (uint_t)(huB.y << 16)) - d2_, d2_);
            hnB.w = fmaf(dec, __builtin_bit_cast(float, huB.y & 0xFFFF0000u) - d3_, d3_);
        }
        *(float4*)(out_h + tile + (size_t)nL * 64 + cA) = hnA;
        *(float4*)(out_h + tile + (size_t)nL * 64 + cB) = hnB;
        uint2 pkA; pkA.x = pk2(hnA.x, hnA.y); pkA.y = pk2(hnA.z, hnA.w);
        uint2 pkB; pkB.x = pk2(hnB.x, hnB.y); pkB.y = pk2(hnB.z, hnB.w);
        *(uint2*)((char*)sIn + SWZ(nL * 256 + cA * 2, nL)) = pkA;
        *(uint2*)((char*)sIn + SWZ(nL * 256 + cB * 2, nL)) = pkB;
        // h-mean partials over this wave's 16 rows (reduce across cl = lane bits 0..3)
        float hA0 = hnA.x, hA1 = hnA.y, hA2 = hnA.z, hA3 = hnA.w;
        float hB0 = hnB.x, hB1 = hnB.y, hB2 = hnB.z, hB3 = hnB.w;
        #pragma unroll
        for (int m = 1; m < 16; m <<= 1) {
            hA0 += __shfl_xor(hA0, m); hA1 += __shfl_xor(hA1, m);
            hA2 += __shfl_xor(hA2, m); hA3 += __shfl_xor(hA3, m);
            hB0 += __shfl_xor(hB0, m); hB1 += __shfl_xor(hB1, m);
            hB2 += __shfl_xor(hB2, m); hB3 += __shfl_xor(hB3, m);
        }
        if (cl == 0) {
            float4 pA = {hA0, hA1, hA2, hA3};
            float4 pB = {hB0, hB1, hB2, hB3};
            *(float4*)&s_scr[rq * 64 + cA] = pA;   // h-part bands [0:256)
            *(float4*)&s_scr[rq * 64 + cB] = pB;
        }
    }
    __syncthreads();   // B4: h_new in sIn visible; sHid reads done

    // ===== msg L1: K=64, wave w owns cols [32w, 32w+32); 1:2 read:MFMA =====
    {
        f4v acc[2][4];
        #pragma unroll
        for (int i = 0; i < 2; i++)
            #pragma unroll
            for (int j = 0; j < 4; j++) acc[i][j] = fzero;
        __builtin_amdgcn_s_setprio(1);
        #pragma unroll
        for (int ks = 0; ks < 2; ks++) {
            const int k0 = ks * 32 + q * 8;
            const s8v aw0 = (ks == 0) ? awP0
                : *(const s8v*)(wm1 + (size_t)(32 * w + cl) * 64 + k0);
            const s8v aw1 = (ks == 0) ? awP1
                : *(const s8v*)(wm1 + (size_t)(32 * w + 16 + cl) * 64 + k0);
            #pragma unroll
            for (int rt = 0; rt < 4; rt++) {
                const int ar = rt * 16 + cl;
                const s8v bi = *(const s8v*)((const char*)sIn + SWZ(ar * 256 + k0 * 2, ar));
                acc[0][rt] = __builtin_amdgcn_mfma_f32_16x16x32_bf16(aw0, bi, acc[0][rt], 0, 0, 0);
                acc[1][rt] = __builtin_amdgcn_mfma_f32_16x16x32_bf16(aw1, bi, acc[1][rt], 0, 0, 0);
            }
        }
        __builtin_amdgcn_s_setprio(0);
        // PREFETCH: msg L2 ks=0 frags (both weight rows)
        awP0 = *(const s8v*)(wm2 + (size_t)dL0 * 256 + q * 8);
        awP1 = *(const s8v*)(wm2 + (size_t)dL1 * 256 + q * 8);
        #pragma unroll
        for (int ct = 0; ct < 2; ct++) {
            const int hc0 = 32 * w + ct * 16 + q * 4;
            const float4 b1 = *(const float4*)&mb1[hc0];
            const float4 g1 = *(const float4*)&mgs1[g * 256 + hc0];
            const float4 o1 = *(const float4*)&mgb1[g * 256 + hc0];
            #pragma unroll
            for (int rt = 0; rt < 4; rt++) {
                const int n = rt * 16 + cl;
                const float t0 = fast_tanh(fmaf(acc[ct][rt][0] + b1.x, g1.x, o1.x));
                const float t1 = fast_tanh(fmaf(acc[ct][rt][1] + b1.y, g1.y, o1.y));
                const float t2 = fast_tanh(fmaf(acc[ct][rt][2] + b1.z, g1.z, o1.z));
                const float t3 = fast_tanh(fmaf(acc[ct][rt][3] + b1.w, g1.w, o1.w));
                uint2 pkd; pkd.x = pk2(t0, t1); pkd.y = pk2(t2, t3);
                *(uint2*)((char*)sHid + SWZ(n * 512 + hc0 * 2, n)) = pkd;
            }
        }
    }
    __syncthreads();   // B5: full mhid visible

    // ===== msg L2: K=256, 2 weight frags x 1 data tile; 8 reads / 16 MFMA =====
    {
        f4v a6[2][2];
        a6[0][0] = fzero; a6[0][1] = fzero; a6[1][0] = fzero; a6[1][1] = fzero;
        __builtin_amdgcn_s_setprio(1);
        #pragma unroll
        for (int ks = 0; ks < 8; ks++) {
            const int k0 = ks * 32 + q * 8;
            const s8v aw0 = (ks == 0) ? awP0 : *(const s8v*)(wm2 + (size_t)dL0 * 256 + k0);
            const s8v aw1 = (ks == 0) ? awP1 : *(const s8v*)(wm2 + (size_t)dL1 * 256 + k0);
            const int ar = rq * 16 + cl;
            const s8v bh = *(const s8v*)((const char*)sHid + SWZ(ar * 512 + k0 * 2, ar));
            a6[0][ks & 1] = __builtin_amdgcn_mfma_f32_16x16x32_bf16(aw0, bh, a6[0][ks & 1], 0, 0, 0);
            a6[1][ks & 1] = __builtin_amdgcn_mfma_f32_16x16x32_bf16(aw1, bh, a6[1][ks & 1], 0, 0, 0);
        }
        __builtin_amdgcn_s_setprio(0);
        // epilogue: msg_new (+nid) for row nL, col-quads cA and cB
        const float4 nvA = *(const float4*)(nidp + (size_t)c * 4096 + (size_t)nL * 64 + cA);
        const float4 nvB = *(const float4*)(nidp + (size_t)c * 4096 + (size_t)nL * 64 + cB);
        const float4 b2A = *(const float4*)&mb2[cA];
        const float4 g2A = *(const float4*)&mgs2[g * 64 + cA];
        const float4 o2A = *(const float4*)&mgb2[g * 64 + cA];
        const float4 b2B = *(const float4*)&mb2[cB];
        const float4 g2B = *(const float4*)&mgs2[g * 64 + cB];
        const float4 o2B = *(const float4*)&mgb2[g * 64 + cB];
        float4 mvA, mvB;
        mvA.x = fast_tanh(fmaf(a6[0][0][0] + a6[0][1][0] + b2A.x, g2A.x, o2A.x)) + nvA.x;
        mvA.y = fast_tanh(fmaf(a6[0][0][1] + a6[0][1][1] + b2A.y, g2A.y, o2A.y)) + nvA.y;
        mvA.z = fast_tanh(fmaf(a6[0][0][2] + a6[0][1][2] + b2A.z, g2A.z, o2A.z)) + nvA.z;
        mvA.w = fast_tanh(fmaf(a6[0][0][3] + a6[0][1][3] + b2A.w, g2A.w, o2A.w)) + nvA.w;
        mvB.x = fast_tanh(fmaf(a6[1][0][0] + a6[1][1][0] + b2B.x, g2B.x, o2B.x)) + nvB.x;
        mvB.y = fast_tanh(fmaf(a6[1][0][1] + a6[1][1][1] + b2B.y, g2B.y, o2B.y)) + nvB.y;
        mvB.z = fast_tanh(fmaf(a6[1][0][2] + a6[1][1][2] + b2B.z, g2B.z, o2B.z)) + nvB.z;
        mvB.w = fast_tanh(fmaf(a6[1][0][3] + a6[1][1][3] + b2B.w, g2B.w, o2B.w)) + nvB.w;
        *(float4*)(out_msg + tile + (size_t)nL * 64 + cA) = mvA;
        *(float4*)(out_msg + tile + (size_t)nL * 64 + cB) = mvB;
        // readout partial: rows 4..7 live in (rq==0, cl=4..7)
        float rA0 = mvA.x, rA1 = mvA.y, rA2 = mvA.z, rA3 = mvA.w;
        float rB0 = mvB.x, rB1 = mvB.y, rB2 = mvB.z, rB3 = mvB.w;
        rA0 += __shfl_xor(rA0, 1); rA1 += __shfl_xor(rA1, 1); rA2 += __shfl_xor(rA2, 1); rA3 += __shfl_xor(rA3, 1);
        rB0 += __shfl_xor(rB0, 1); rB1 += __shfl_xor(rB1, 1); rB2 += __shfl_xor(rB2, 1); rB3 += __shfl_xor(rB3, 1);
        rA0 += __shfl_xor(rA0, 2); rA1 += __shfl_xor(rA1, 2); rA2 += __shfl_xor(rA2, 2); rA3 += __shfl_xor(rA3, 2);
        rB0 += __shfl_xor(rB0, 2); rB1 += __shfl_xor(rB1, 2); rB2 += __shfl_xor(rB2, 2); rB3 += __shfl_xor(rB3, 2);
        if (rq == 0 && cl == 4) {
            float4 oA = {rA0 * 0.5f, rA1 * 0.5f, rA2 * 0.5f, rA3 * 0.5f};
            float4 oB = {rB0 * 0.5f, rB1 * 0.5f, rB2 * 0.5f, rB3 * 0.5f};
            *(float4*)(out_read + ((size_t)b * NCC + c) * 64 + cA) = oA;
            *(float4*)(out_read + ((size_t)b * NCC + c) * 64 + cB) = oB;
        }
        // m-mean partials over this wave's 16 rows
        float mA0 = mvA.x, mA1 = mvA.y, mA2 = mvA.z, mA3 = mvA.w;
        float mB0 = mvB.x, mB1 = mvB.y, mB2 = mvB.z, mB3 = mvB.w;
        #pragma unroll
        for (int m = 1; m < 16; m <<= 1) {
            mA0 += __shfl_xor(mA0, m); mA1 += __shfl_xor(mA1, m);
            mA2 += __shfl_xor(mA2, m); mA3 += __shfl_xor(mA3, m);
            mB0 += __shfl_xor(mB0, m); mB1 += __shfl_xor(mB1, m);
            mB2 += __shfl_xor(mB2, m); mB3 += __shfl_xor(mB3, m);
        }
        if (cl == 0) {
            float4 pA = {mA0, mA1, mA2, mA3};
            float4 pB = {mB0, mB1, mB2, mB3};
            *(float4*)&s_scr[256 + rq * 64 + cA] = pA;   // m-part bands [256:512)
            *(float4*)&s_scr[256 + rq * 64 + cB] = pB;
        }
    }
    __syncthreads();   // B6

    // ================= P7: feats record (130 values) =================
    if (t < 132) {
        float v = 0.f;
        if (t < 64) {
            v = (s_scr[t] + s_scr[64 + t] + s_scr[128 + t] + s_scr[192 + t]) * (1.f / 64.f);
        } else if (t < 128) {
            const int dd = t - 64;
            v = (s_scr[256 + dd] + s_scr[320 + dd] + s_scr[384 + dd] + s_scr[448 + dd]) * (1.f / 64.f);
        } else if (t == 128) {
            v = (s_wsum[0] + s_wsum[1] + s_wsum[2] + s_wsum[3]
               + s_wsum[4] + s_wsum[5] + s_wsum[6] + s_wsum[7]) * (1.f / 4096.f);
        } else if (t == 129) v = s_dsum * (1.f / 64.f);
        wsf[(size_t)bc * 132 + t] = v;
    }
}

// ---------------------------------------------------------------------------
// Kernel 2: per-cell modulation MLP (distinct weights per cell)
// ---------------------------------------------------------------------------
__global__ __launch_bounds__(256, 2)
void mg_mod_kernel(
    const float* __restrict__ wsf,   const float* __restrict__ modw1,
    const float* __restrict__ modb1, const float* __restrict__ modw2,
    const float* __restrict__ modb2, const float* __restrict__ ctxp,
    const float* __restrict__ bglp,  float* __restrict__ out_ctx,
    float* __restrict__ out_bg)
{
    const int c = blockIdx.x;
    const int t = threadIdx.x;
    __shared__ float s_f[8][MODIN];
    __shared__ float s_h2[8][HMODL];

    for (int k = t; k < 8 * MODIN; k += 256) {
        const int b = k / MODIN, f = k - b * MODIN;
        float v;
        if (f < 130)      v = wsf[((size_t)b * NCC + c) * 132 + f];
        else if (f < 194) v = ctxp[((size_t)b * NCC + c) * 64 + (f - 130)];
        else              v = bglp[((size_t)b * NCC + c) * 4 + (f - 194)];
        s_f[b][f] = v;
    }
    __syncthreads();

    {
        const int hh = t & 127, bh = (t >> 7) * 4;
        float a0 = 0.f, a1 = 0.f, a2 = 0.f, a3 = 0.f;
        const float* wp = modw1 + (size_t)c * MODIN * HMODL + hh;
        for (int f = 0; f < MODIN; f++) {
            const float wv = wp[(size_t)f * HMODL];
            a0 = fmaf(s_f[bh + 0][f], wv, a0);
            a1 = fmaf(s_f[bh + 1][f], wv, a1);
            a2 = fmaf(s_f[bh + 2][f], wv, a2);
            a3 = fmaf(s_f[bh + 3][f], wv, a3);
        }
        const float bv = modb1[(size_t)c * HMODL + hh];
        s_h2[bh + 0][hh] = fast_tanh(a0 + bv);
        s_h2[bh + 1][hh] = fast_tanh(a1 + bv);
        s_h2[bh + 2][hh] = fast_tanh(a2 + bv);
        s_h2[bh + 3][hh] = fast_tanh(a3 + bv);
    }
    __syncthreads();

    for (int idx = t; idx < 8 * MODOUT; idx += 256) {
        const int b = idx / MODOUT, o = idx - b * MODOUT;
        float acc = modb2[(size_t)c * MODOUT + o];
        const float* wp = modw2 + (size_t)c * HMODL * MODOUT + o;
        const float* hrow = s_h2[b];
        for (int hh = 0; hh < HMODL; hh++)
            acc = fmaf(hrow[hh], wp[(size_t)hh * MODOUT], acc);
        if (o < 64)
            out_ctx[((size_t)b * NCC + c) * 64 + o] =
                ctxp[((size_t)b * NCC + c) * 64 + o] + acc;
        else
            out_bg[((size_t)b * NCC + c) * 4 + (o - 64)] =
                bglp[((size_t)b * NCC + c) * 4 + (o - 64)] + acc;
    }
}

extern "C" void kernel_launch(void* const* d_in, const int* in_sizes, int n_in,
                              void* d_out, int out_size, void* d_ws, size_t ws_size,
                              hipStream_t stream) {
    const float* xp     = (const float*)d_in[0];
    const float* hp     = (const float*)d_in[1];
    const float* msgp   = (const float*)d_in[2];
    const float* Wp     = (const float*)d_in[3];
    const float* decayp = (const float*)d_in[4];
    const float* ctxp   = (const float*)d_in[5];
    const float* bglp   = (const float*)d_in[6];
    const float* nidp   = (const float*)d_in[7];
    const float* sw1    = (const float*)d_in[8];
    const float* sb1    = (const float*)d_in[9];
    const float* sgs1   = (const float*)d_in[10];
    const float* sgb1   = (const float*)d_in[11];
    const float* sw2    = (const float*)d_in[12];
    const float* sb2    = (const float*)d_in[13];
    const float* sgs2   = (const float*)d_in[14];
    const float* sgb2   = (const float*)d_in[15];
    const float* mw1    = (const float*)d_in[16];
    const float* mb1    = (const float*)d_in[17];
    const float* mgs1   = (const float*)d_in[18];
    const float* mgb1   = (const float*)d_in[19];
    const float* mw2    = (const float*)d_in[20];
    const float* mb2    = (const float*)d_in[21];
    const float* mgs2   = (const float*)d_in[22];
    const float* mgb2   = (const float*)d_in[23];
    const float* iw     = (const float*)d_in[24];
    const float* ibias  = (const float*)d_in[25];
    const float* modw1  = (const float*)d_in[26];
    const float* modb1  = (const float*)d_in[27];
    const float* modw2  = (const float*)d_in[28];
    const float* modb2  = (const float*)d_in[29];
    const int*   c2g    = (const int*)d_in[30];

    float* out      = (float*)d_out;
    float* out_read = out;                 // 524288
    float* out_h    = out_read + 524288;   // 33554432
    float* out_msg  = out_h + 33554432;    // 33554432
    float* out_ctx  = out_msg + 33554432;  // 524288
    float* out_bg   = out_ctx + 524288;    // 32768

    ushort_t* wb  = (ushort_t*)d_ws;                          // 160KB bf16 weights
    float*    wsf = (float*)((char*)d_ws + FEATS_BYTE_OFF);   // 8192 x 132 f32

    mg_cvtw<<<320, 256, 0, stream>>>(sw1, sw2, mw1, mw2, wb);

    // inject -> head of each out_h tile (read by P1, overwritten by state epilogue)
    mg_inject<<<1024, 256, 0, stream>>>(xp, iw, ibias, c2g, out_h);

    mg_cell_kernel<<<8192, 512, 0, stream>>>(
        hp, msgp, Wp, decayp, bglp, nidp,
        sb1, sgs1, sgb1, sb2, sgs2, sgb2,
        mb1, mgs1, mgb1, mb2, mgs2, mgb2,
        c2g, wb, out_read, out_h, out_msg, wsf);

    mg_mod_kernel<<<1024, 256, 0, stream>>>(
        wsf, modw1, modb1, modw2, modb2, ctxp, bglp, out_ctx, out_bg);
}

// Round 20
// 394.022 us; speedup vs baseline: 1.3048x; 1.3048x over previous
//
#include <hip/hip_runtime.h>

#define NCC 1024
#define MODIN 198
#define MODOUT 68
#define HMODL 128

typedef __attribute__((ext_vector_type(8))) short s8v;   // 8 bf16 = 4 VGPR
typedef __attribute__((ext_vector_type(4))) float f4v;   // MFMA acc
typedef unsigned short ushort_t;
typedef unsigned int uint_t;

#define OFF_SW1 0
#define OFF_SW2 32768
#define OFF_MW1 49152
#define OFF_MW2 65536
#define FEATS_BYTE_OFF 262144   // feats: 8192 cells x 132 f32

__device__ __forceinline__ float fast_tanh(float x) {
    const float e = __builtin_amdgcn_exp2f(x * 2.885390081777927f);   // e^{2x}
    const float r = __builtin_amdgcn_rcpf(e + 1.f);
    return fmaf(-2.f, r, 1.f);
}
__device__ __forceinline__ float fast_sigmoid(float x) {
    const float e = __builtin_amdgcn_exp2f(x * -1.4426950408889634f);
    return __builtin_amdgcn_rcpf(e + 1.f);
}
__device__ __forceinline__ ushort_t f2bf(float x) {   // RNE f32->bf16 (scalar path)
    uint_t u = __builtin_bit_cast(uint_t, x);
    u += 0x7FFFu + ((u >> 16) & 1u);
    return (ushort_t)(u >> 16);
}
__device__ __forceinline__ uint_t pk2(float a, float b) {   // HW pack: 1 instr, RNE
    uint_t r;
    asm("v_cvt_pk_bf16_f32 %0, %1, %2" : "=v"(r) : "v"(a), "v"(b));
    return r;
}
// XOR swizzle on LDS byte offsets (16B granule)
#define SWZ(byteoff, row) ((byteoff) ^ (((row) & 7) << 4))

// ---------------------------------------------------------------------------
// Kernel 0: weights -> bf16 once per launch
// ---------------------------------------------------------------------------
__global__ __launch_bounds__(256)
void mg_cvtw(const float* __restrict__ sw1, const float* __restrict__ sw2,
             const float* __restrict__ mw1, const float* __restrict__ mw2,
             ushort_t* __restrict__ o) {
    const int i = blockIdx.x * 256 + threadIdx.x;   // grid 320 -> 81920 exact
    float v;
    if (i < 32768)      v = sw1[i];
    else if (i < 49152) v = sw2[i - 32768];
    else if (i < 65536) v = mw1[i - 49152];
    else                v = mw2[i - 65536];
    o[i] = f2bf(v);
}

// ---------------------------------------------------------------------------
// Kernel 0b: inject[b,c,o] -> head of each out_h tile (read by P1)
// ---------------------------------------------------------------------------
__global__ __launch_bounds__(256, 4)
void mg_inject(const float* __restrict__ xp, const float* __restrict__ iw,
               const float* __restrict__ ibias, const int* __restrict__ c2g,
               float* __restrict__ injb) {
    const int c = blockIdx.x, t = threadIdx.x;
    const int g = c2g[c];
    __shared__ float s_x[8][64];
    for (int idx = t; idx < 512; idx += 256)
        s_x[idx >> 6][idx & 63] = xp[(size_t)(idx >> 6) * (NCC * 64) + c * 64 + (idx & 63)];
    __syncthreads();
    const float* wrow = iw + (size_t)g * 16384 + t * 64;
    float a0 = 0.f, a1 = 0.f, a2 = 0.f, a3 = 0.f, a4 = 0.f, a5 = 0.f, a6 = 0.f, a7 = 0.f;
    #pragma unroll
    for (int i = 0; i < 64; i += 4) {
        const float4 w4 = *(const float4*)(wrow + i);
        const float4 x0 = *(const float4*)&s_x[0][i];
        const float4 x1 = *(const float4*)&s_x[1][i];
        const float4 x2 = *(const float4*)&s_x[2][i];
        const float4 x3 = *(const float4*)&s_x[3][i];
        const float4 x4 = *(const float4*)&s_x[4][i];
        const float4 x5 = *(const float4*)&s_x[5][i];
        const float4 x6 = *(const float4*)&s_x[6][i];
        const float4 x7 = *(const float4*)&s_x[7][i];
        a0 = fmaf(w4.x, x0.x, a0); a0 = fmaf(w4.y, x0.y, a0); a0 = fmaf(w4.z, x0.z, a0); a0 = fmaf(w4.w, x0.w, a0);
        a1 = fmaf(w4.x, x1.x, a1); a1 = fmaf(w4.y, x1.y, a1); a1 = fmaf(w4.z, x1.z, a1); a1 = fmaf(w4.w, x1.w, a1);
        a2 = fmaf(w4.x, x2.x, a2); a2 = fmaf(w4.y, x2.y, a2); a2 = fmaf(w4.z, x2.z, a2); a2 = fmaf(w4.w, x2.w, a2);
        a3 = fmaf(w4.x, x3.x, a3); a3 = fmaf(w4.y, x3.y, a3); a3 = fmaf(w4.z, x3.z, a3); a3 = fmaf(w4.w, x3.w, a3);
        a4 = fmaf(w4.x, x4.x, a4); a4 = fmaf(w4.y, x4.y, a4); a4 = fmaf(w4.z, x4.z, a4); a4 = fmaf(w4.w, x4.w, a4);
        a5 = fmaf(w4.x, x5.x, a5); a5 = fmaf(w4.y, x5.y, a5); a5 = fmaf(w4.z, x5.z, a5); a5 = fmaf(w4.w, x5.w, a5);
        a6 = fmaf(w4.x, x6.x, a6); a6 = fmaf(w4.y, x6.y, a6); a6 = fmaf(w4.z, x6.z, a6); a6 = fmaf(w4.w, x6.w, a6);
        a7 = fmaf(w4.x, x7.x, a7); a7 = fmaf(w4.y, x7.y, a7); a7 = fmaf(w4.z, x7.z, a7); a7 = fmaf(w4.w, x7.w, a7);
    }
    const float bv = ibias[g * 256 + t];
    const float acc[8] = {a0, a1, a2, a3, a4, a5, a6, a7};
    #pragma unroll
    for (int b = 0; b < 8; b++)
        injb[((size_t)b * NCC + c) * 4096 + t] = acc[b] + bv;
}

// ---------------------------------------------------------------------------
// Kernel 1: per (b, cell) block; 512 threads = 8 waves; FULL sHid [64][256]
// (6 barriers), operand-swapped MFMAs, cvt_pk, cross-barrier prefetch.
// L1 phases: each wave owns 32 output cols (2 weight frags/ks) so each data
// B-frag LDS read feeds TWO MFMAs (ds_read:MFMA = 1:2).  [round-18 optimum]
// ---------------------------------------------------------------------------
__global__ __launch_bounds__(512, 4)
void mg_cell_kernel(
    const float* __restrict__ hp,   const float* __restrict__ msgp,
    const float* __restrict__ Wp,   const float* __restrict__ decayp,
    const float* __restrict__ bglp, const float* __restrict__ nidp,
    const float* __restrict__ sb1,  const float* __restrict__ sgs1,
    const float* __restrict__ sgb1, const float* __restrict__ sb2,
    const float* __restrict__ sgs2, const float* __restrict__ sgb2,
    const float* __restrict__ mb1,  const float* __restrict__ mgs1,
    const float* __restrict__ mgb1, const float* __restrict__ mb2,
    const float* __restrict__ mgs2, const float* __restrict__ mgb2,
    const int*   __restrict__ c2g,  const ushort_t* __restrict__ wb,
    float* __restrict__ out_read, float* __restrict__ out_h,
    float* __restrict__ out_msg,  float* __restrict__ wsf)
{
    const int t  = threadIdx.x;
    const int bc = blockIdx.x;
    const int b  = bc >> 10, c = bc & 1023;
    const int gh = c >> 5, gwc = c & 31;
    const int lane = t & 63, w = t >> 6;
    const int cl = lane & 15, q = lane >> 4;
    const int g  = c2g[c];
    const size_t tile = (size_t)bc * 4096;

    __shared__ ushort_t sHid[16384];   // [64][256] bf16 32KB; first 16KB overlays sW|sMsgT
    __shared__ ushort_t sIn[8192];     // [64][128] bf16: [received/h_new | h]
    __shared__ float s_scr[256];       // border; later h-part[2][64] @0, m-part[2][64] @128
    __shared__ float s_dec[64];
    __shared__ float s_wsum[8];
    __shared__ float s_dsum;

    ushort_t* sW    = sHid;            // [64][64], row stride 128B
    ushort_t* sMsgT = sHid + 4096;     // [64 d][64 m]

    // ================= P0: staging + border + decay =================
    {   // W -> sW bf16 (+ sum|W|): n = t>>3, 8 cols each
        const int n = t >> 3, m0 = (t & 7) * 8;
        const float* src = Wp + tile + n * 64 + m0;
        const float4 v0 = *(const float4*)(src);
        const float4 v1 = *(const float4*)(src + 4);
        float wsum = fabsf(v0.x) + fabsf(v0.y) + fabsf(v0.z) + fabsf(v0.w)
                   + fabsf(v1.x) + fabsf(v1.y) + fabsf(v1.z) + fabsf(v1.w);
        *(uint_t*)((char*)sW + SWZ(n * 128 + (m0 + 0) * 2, n)) = pk2(v0.x, v0.y);
        *(uint_t*)((char*)sW + SWZ(n * 128 + (m0 + 2) * 2, n)) = pk2(v0.z, v0.w);
        *(uint_t*)((char*)sW + SWZ(n * 128 + (m0 + 4) * 2, n)) = pk2(v1.x, v1.y);
        *(uint_t*)((char*)sW + SWZ(n * 128 + (m0 + 6) * 2, n)) = pk2(v1.z, v1.w);
        #pragma unroll
        for (int off = 32; off > 0; off >>= 1) wsum += __shfl_down(wsum, off);
        if (lane == 0) s_wsum[w] = wsum;
    }
    #pragma unroll
    for (int i = 0; i < 2; i++) {   // msg^T -> sMsgT bf16
        const int m = (t >> 4) + i * 32, d0 = (t & 15) * 4;
        const float4 v = *(const float4*)(msgp + tile + (size_t)m * 64 + d0);
        *(ushort_t*)((char*)sMsgT + SWZ((d0 + 0) * 128 + m * 2, d0 + 0)) = f2bf(v.x);
        *(ushort_t*)((char*)sMsgT + SWZ((d0 + 1) * 128 + m * 2, d0 + 1)) = f2bf(v.y);
        *(ushort_t*)((char*)sMsgT + SWZ((d0 + 2) * 128 + m * 2, d0 + 2)) = f2bf(v.z);
        *(ushort_t*)((char*)sMsgT + SWZ((d0 + 3) * 128 + m * 2, d0 + 3)) = f2bf(v.w);
    }
    #pragma unroll
    for (int i = 0; i < 2; i++) {   // h -> sIn[:,64:128] bf16
        const int n = (t >> 4) + i * 32, d0 = (t & 15) * 4;
        const float4 v = *(const float4*)(hp + tile + (size_t)n * 64 + d0);
        *(uint_t*)((char*)sIn + SWZ(n * 256 + (64 + d0) * 2, n))     = pk2(v.x, v.y);
        *(uint_t*)((char*)sIn + SWZ(n * 256 + (64 + d0 + 2) * 2, n)) = pk2(v.z, v.w);
    }
    if (t < 256) {   // gated border incoming: wave p = w (0..3)
        const int p = w, dd = lane;
        int ok, nc2, qq;
        if      (p == 0) { ok = (gh > 0);   nc2 = c - 32; qq = 1; }
        else if (p == 1) { ok = (gh < 31);  nc2 = c + 32; qq = 0; }
        else if (p == 2) { ok = (gwc > 0);  nc2 = c - 1;  qq = 3; }
        else             { ok = (gwc < 31); nc2 = c + 1;  qq = 2; }
        float v = 0.f;
        if (ok) v = msgp[((size_t)b * NCC + nc2) * 4096 + (8 + qq) * 64 + dd];
        s_scr[p * 64 + dd] = fast_sigmoid(bglp[(size_t)bc * 4 + p]) * v;
    }
    if (w == 4) {   // decay sigmoid table + logit sum
        const float dl = decayp[(size_t)bc * 64 + lane];
        s_dec[lane] = fast_sigmoid(dl);
        float v = dl;
        #pragma unroll
        for (int off = 32; off > 0; off >>= 1) v += __shfl_down(v, off);
        if (lane == 0) s_dsum = v;
    }
    __syncthreads();   // B1

    const f4v fzero = {0.f, 0.f, 0.f, 0.f};
    const int d0 = 16 * (w & 3) + q * 4;   // 4 output cols (L2 epilogues)
    const int dA = 16 * (w & 3) + cl;      // L2 weight-row index
    const int rh = w >> 2;                 // row-half (L2 phases, P1)
    const ushort_t* wb1 = wb + OFF_SW1;
    const ushort_t* wb2 = wb + OFF_SW2;
    const ushort_t* wm1 = wb + OFF_MW1;
    const ushort_t* wm2 = wb + OFF_MW2;

    s8v awP0, awP1;   // cross-barrier first-fragment prefetch pair

    // ========== P1: received^ = mfma(msgT, W) + inject + border -> sIn[:,0:64] ==========
    {
        f4v wm[2] = {fzero, fzero};
        __builtin_amdgcn_s_setprio(1);
        #pragma unroll
        for (int ks = 0; ks < 2; ks++) {
            const int k0 = ks * 32 + q * 8;
            const s8v am = *(const s8v*)((const char*)sMsgT + SWZ(dA * 128 + k0 * 2, dA));
            #pragma unroll
            for (int nt = 0; nt < 2; nt++) {
                const int ar = (rh * 2 + nt) * 16 + cl;
                const s8v bw = *(const s8v*)((const char*)sW + SWZ(ar * 128 + k0 * 2, ar));
                wm[nt] = __builtin_amdgcn_mfma_f32_16x16x32_bf16(am, bw, wm[nt], 0, 0, 0);
            }
        }
        __builtin_amdgcn_s_setprio(0);
        // PREFETCH: state L1 ks=0 frags (ct=0,1); drained by B2
        awP0 = *(const s8v*)(wb1 + (size_t)(32 * w + cl) * 128 + q * 8);
        awP1 = *(const s8v*)(wb1 + (size_t)(32 * w + 16 + cl) * 128 + q * 8);
        #pragma unroll
        for (int nt = 0; nt < 2; nt++) {
            const int n = (rh * 2 + nt) * 16 + cl;
            float v0 = wm[nt][0], v1 = wm[nt][1], v2 = wm[nt][2], v3 = wm[nt][3];
            if (n < 4) {
                const float4 inj = *(const float4*)(out_h + tile + (size_t)n * 64 + d0);
                v0 += inj.x; v1 += inj.y; v2 += inj.z; v3 += inj.w;
            } else if (n >= 8 && n < 12) {
                const float4 bin = *(const float4*)&s_scr[(n - 8) * 64 + d0];
                v0 += bin.x; v1 += bin.y; v2 += bin.z; v3 += bin.w;
            }
            uint2 pkd; pkd.x = pk2(v0, v1); pkd.y = pk2(v2, v3);
            *(uint2*)((char*)sIn + SWZ(n * 256 + d0 * 2, n)) = pkd;
        }
    }
    __syncthreads();   // B2 (sW/sMsgT reads done -> sHid full overlay safe)

    // ===== state L1: K=128, wave w owns cols [32w, 32w+32); 16 reads / 32 MFMA =====
    {
        f4v acc[2][4];
        #pragma unroll
        for (int i = 0; i < 2; i++)
            #pragma unroll
            for (int j = 0; j < 4; j++) acc[i][j] = fzero;
        __builtin_amdgcn_s_setprio(1);
        #pragma unroll
        for (int ks = 0; ks < 4; ks++) {
            const int k0 = ks * 32 + q * 8;
            const s8v aw0 = (ks == 0) ? awP0
                : *(const s8v*)(wb1 + (size_t)(32 * w + cl) * 128 + k0);
            const s8v aw1 = (ks == 0) ? awP1
                : *(const s8v*)(wb1 + (size_t)(32 * w + 16 + cl) * 128 + k0);
            #pragma unroll
            for (int rt = 0; rt < 4; rt++) {
                const int ar = rt * 16 + cl;
                const s8v bi = *(const s8v*)((const char*)sIn + SWZ(ar * 256 + k0 * 2, ar));
                acc[0][rt] = __builtin_amdgcn_mfma_f32_16x16x32_bf16(aw0, bi, acc[0][rt], 0, 0, 0);
                acc[1][rt] = __builtin_amdgcn_mfma_f32_16x16x32_bf16(aw1, bi, acc[1][rt], 0, 0, 0);
            }
        }
        __builtin_amdgcn_s_setprio(0);
        // PREFETCH: state L2 ks=0,1 frags
        awP0 = *(const s8v*)(wb2 + (size_t)dA * 256 + q * 8);
        awP1 = *(const s8v*)(wb2 + (size_t)dA * 256 + 32 + q * 8);
        #pragma unroll
        for (int ct = 0; ct < 2; ct++) {
            const int hc0 = 32 * w + ct * 16 + q * 4;
            const float4 b1 = *(const float4*)&sb1[hc0];
            const float4 g1 = *(const float4*)&sgs1[g * 256 + hc0];
            const float4 o1 = *(const float4*)&sgb1[g * 256 + hc0];
            #pragma unroll
            for (int rt = 0; rt < 4; rt++) {
                const int n = rt * 16 + cl;
                const float t0 = fast_tanh(fmaf(acc[ct][rt][0] + b1.x, g1.x, o1.x));
                const float t1 = fast_tanh(fmaf(acc[ct][rt][1] + b1.y, g1.y, o1.y));
                const float t2 = fast_tanh(fmaf(acc[ct][rt][2] + b1.z, g1.z, o1.z));
                const float t3 = fast_tanh(fmaf(acc[ct][rt][3] + b1.w, g1.w, o1.w));
                uint2 pkd; pkd.x = pk2(t0, t1); pkd.y = pk2(t2, t3);
                *(uint2*)((char*)sHid + SWZ(n * 512 + hc0 * 2, n)) = pkd;
            }
        }
    }
    __syncthreads();   // B3: full hid visible

    // ===== state L2: K=256 single pass + h_new epilogue =====
    {
        f4v a2[2][2];
        a2[0][0] = fzero; a2[0][1] = fzero; a2[1][0] = fzero; a2[1][1] = fzero;
        __builtin_amdgcn_s_setprio(1);
        #pragma unroll
        for (int ks = 0; ks < 8; ks++) {
            const int k0 = ks * 32 + q * 8;
            const s8v aw = (ks == 0) ? awP0 : (ks == 1) ? awP1
                : *(const s8v*)(wb2 + (size_t)dA * 256 + k0);
            #pragma unroll
            for (int nt = 0; nt < 2; nt++) {
                const int ar = (rh * 2 + nt) * 16 + cl;
                const s8v bh = *(const s8v*)((const char*)sHid + SWZ(ar * 512 + k0 * 2, ar));
                a2[nt][ks & 1] = __builtin_amdgcn_mfma_f32_16x16x32_bf16(aw, bh, a2[nt][ks & 1], 0, 0, 0);
            }
        }
        __builtin_amdgcn_s_setprio(0);
        // PREFETCH: msg L1 ks=0 frags (ct=0,1)
        awP0 = *(const s8v*)(wm1 + (size_t)(32 * w + cl) * 64 + q * 8);
        awP1 = *(const s8v*)(wm1 + (size_t)(32 * w + 16 + cl) * 64 + q * 8);
        // epilogue: cand -> h_new (float4 global + packed sIn) + h_mean partials
        const float4 b2 = *(const float4*)&sb2[d0];
        const float4 g2 = *(const float4*)&sgs2[g * 64 + d0];
        const float4 o2 = *(const float4*)&sgb2[g * 64 + d0];
        float hs0 = 0.f, hs1 = 0.f, hs2 = 0.f, hs3 = 0.f;
        #pragma unroll
        for (int nt = 0; nt < 2; nt++) {
            const int n = (rh * 2 + nt) * 16 + cl;
            const float dec = s_dec[n];
            const uint2 hu = *(const uint2*)((const char*)sIn + SWZ(n * 256 + (64 + d0) * 2, n));
            const float hv0 = __builtin_bit_cast(float, (uint_t)(hu.x << 16));
            const float hv1 = __builtin_bit_cast(float, hu.x & 0xFFFF0000u);
            const float hv2 = __builtin_bit_cast(float, (uint_t)(hu.y << 16));
            const float hv3 = __builtin_bit_cast(float, hu.y & 0xFFFF0000u);
            const float c0 = fast_tanh(fmaf(a2[nt][0][0] + a2[nt][1][0] + b2.x, g2.x, o2.x));
            const float c1 = fast_tanh(fmaf(a2[nt][0][1] + a2[nt][1][1] + b2.y, g2.y, o2.y));
            const float c2 = fast_tanh(fmaf(a2[nt][0][2] + a2[nt][1][2] + b2.z, g2.z, o2.z));
            const float c3 = fast_tanh(fmaf(a2[nt][0][3] + a2[nt][1][3] + b2.w, g2.w, o2.w));
            float4 hn;
            hn.x = fmaf(dec, hv0 - c0, c0);
            hn.y = fmaf(dec, hv1 - c1, c1);
            hn.z = fmaf(dec, hv2 - c2, c2);
            hn.w = fmaf(dec, hv3 - c3, c3);
            *(float4*)(out_h + tile + (size_t)n * 64 + d0) = hn;
            uint2 pkd; pkd.x = pk2(hn.x, hn.y); pkd.y = pk2(hn.z, hn.w);
            *(uint2*)((char*)sIn + SWZ(n * 256 + d0 * 2, n)) = pkd;
            hs0 += hn.x; hs1 += hn.y; hs2 += hn.z; hs3 += hn.w;
        }
        #pragma unroll
        for (int m = 1; m < 16; m <<= 1) {
            hs0 += __shfl_xor(hs0, m); hs1 += __shfl_xor(hs1, m);
            hs2 += __shfl_xor(hs2, m); hs3 += __shfl_xor(hs3, m);
        }
        if (cl == 0) {
            float4 hp4 = {hs0, hs1, hs2, hs3};
            *(float4*)&s_scr[rh * 64 + d0] = hp4;   // h-part bands [0:128)
        }
    }
    __syncthreads();   // B4: h_new in sIn visible; sHid reads done

    // ===== msg L1: K=64, wave w owns cols [32w, 32w+32); 8 reads / 16 MFMA =====
    {
        f4v acc[2][4];
        #pragma unroll
        for (int i = 0; i < 2; i++)
            #pragma unroll
            for (int j = 0; j < 4; j++) acc[i][j] = fzero;
        __builtin_amdgcn_s_setprio(1);
        #pragma unroll
        for (int ks = 0; ks < 2; ks++) {
            const int k0 = ks * 32 + q * 8;
            const s8v aw0 = (ks == 0) ? awP0
                : *(const s8v*)(wm1 + (size_t)(32 * w + cl) * 64 + k0);
            const s8v aw1 = (ks == 0) ? awP1
                : *(const s8v*)(wm1 + (size_t)(32 * w + 16 + cl) * 64 + k0);
            #pragma unroll
            for (int rt = 0; rt < 4; rt++) {
                const int ar = rt * 16 + cl;
                const s8v bi = *(const s8v*)((const char*)sIn + SWZ(ar * 256 + k0 * 2, ar));
                acc[0][rt] = __builtin_amdgcn_mfma_f32_16x16x32_bf16(aw0, bi, acc[0][rt], 0, 0, 0);
                acc[1][rt] = __builtin_amdgcn_mfma_f32_16x16x32_bf16(aw1, bi, acc[1][rt], 0, 0, 0);
            }
        }
        __builtin_amdgcn_s_setprio(0);
        // PREFETCH: msg L2 ks=0,1 frags
        awP0 = *(const s8v*)(wm2 + (size_t)dA * 256 + q * 8);
        awP1 = *(const s8v*)(wm2 + (size_t)dA * 256 + 32 + q * 8);
        #pragma unroll
        for (int ct = 0; ct < 2; ct++) {
            const int hc0 = 32 * w + ct * 16 + q * 4;
            const float4 b1 = *(const float4*)&mb1[hc0];
            const float4 g1 = *(const float4*)&mgs1[g * 256 + hc0];
            const float4 o1 = *(const float4*)&mgb1[g * 256 + hc0];
            #pragma unroll
            for (int rt = 0; rt < 4; rt++) {
                const int n = rt * 16 + cl;
                const float t0 = fast_tanh(fmaf(acc[ct][rt][0] + b1.x, g1.x, o1.x));
                const float t1 = fast_tanh(fmaf(acc[ct][rt][1] + b1.y, g1.y, o1.y));
                const float t2 = fast_tanh(fmaf(acc[ct][rt][2] + b1.z, g1.z, o1.z));
                const float t3 = fast_tanh(fmaf(acc[ct][rt][3] + b1.w, g1.w, o1.w));
                uint2 pkd; pkd.x = pk2(t0, t1); pkd.y = pk2(t2, t3);
                *(uint2*)((char*)sHid + SWZ(n * 512 + hc0 * 2, n)) = pkd;
            }
        }
    }
    __syncthreads();   // B5: full mhid visible

    // ===== msg L2: K=256 single pass + msg epilogue =====
    {
        f4v a6[2][2];
        a6[0][0] = fzero; a6[0][1] = fzero; a6[1][0] = fzero; a6[1][1] = fzero;
        __builtin_amdgcn_s_setprio(1);
        #pragma unroll
        for (int ks = 0; ks < 8; ks++) {
            const int k0 = ks * 32 + q * 8;
            const s8v aw = (ks == 0) ? awP0 : (ks == 1) ? awP1
                : *(const s8v*)(wm2 + (size_t)dA * 256 + k0);
            #pragma unroll
            for (int nt = 0; nt < 2; nt++) {
                const int ar = (rh * 2 + nt) * 16 + cl;
                const s8v bh = *(const s8v*)((const char*)sHid + SWZ(ar * 512 + k0 * 2, ar));
                a6[nt][ks & 1] = __builtin_amdgcn_mfma_f32_16x16x32_bf16(aw, bh, a6[nt][ks & 1], 0, 0, 0);
            }
        }
        __builtin_amdgcn_s_setprio(0);
        // epilogue: msg_new (+nid, float4 stores), mmean partials, readout
        const float4 b2 = *(const float4*)&mb2[d0];
        const float4 g2 = *(const float4*)&mgs2[g * 64 + d0];
        const float4 o2 = *(const float4*)&mgb2[g * 64 + d0];
        float ms0 = 0.f, ms1 = 0.f, ms2 = 0.f, ms3 = 0.f;
        float ro0 = 0.f, ro1 = 0.f, ro2 = 0.f, ro3 = 0.f;
        #pragma unroll
        for (int nt = 0; nt < 2; nt++) {
            const int n = (rh * 2 + nt) * 16 + cl;
            const float4 nv = *(const float4*)(nidp + (size_t)c * 4096 + (size_t)n * 64 + d0);
            float4 mv;
            mv.x = fast_tanh(fmaf(a6[nt][0][0] + a6[nt][1][0] + b2.x, g2.x, o2.x)) + nv.x;
            mv.y = fast_tanh(fmaf(a6[nt][0][1] + a6[nt][1][1] + b2.y, g2.y, o2.y)) + nv.y;
            mv.z = fast_tanh(fmaf(a6[nt][0][2] + a6[nt][1][2] + b2.z, g2.z, o2.z)) + nv.z;
            mv.w = fast_tanh(fmaf(a6[nt][0][3] + a6[nt][1][3] + b2.w, g2.w, o2.w)) + nv.w;
            *(float4*)(out_msg + tile + (size_t)n * 64 + d0) = mv;
            ms0 += mv.x; ms1 += mv.y; ms2 += mv.z; ms3 += mv.w;
            if (nt == 0 && rh == 0 && n >= 4 && n < 8) {
                ro0 = mv.x; ro1 = mv.y; ro2 = mv.z; ro3 = mv.w;
            }
        }
        #pragma unroll
        for (int m = 1; m < 16; m <<= 1) {
            ms0 += __shfl_xor(ms0, m); ms1 += __shfl_xor(ms1, m);
            ms2 += __shfl_xor(ms2, m); ms3 += __shfl_xor(ms3, m);
        }
        if (cl == 0) {
            float4 mp4 = {ms0, ms1, ms2, ms3};
            *(float4*)&s_scr[128 + rh * 64 + d0] = mp4;   // m-part bands [128:256)
        }
        // readout: sum over n=4..7 (lanes cl=4..7, rh==0)
        ro0 += __shfl_xor(ro0, 1); ro1 += __shfl_xor(ro1, 1);
        ro2 += __shfl_xor(ro2, 1); ro3 += __shfl_xor(ro3, 1);
        ro0 += __shfl_xor(ro0, 2); ro1 += __shfl_xor(ro1, 2);
        ro2 += __shfl_xor(ro2, 2); ro3 += __shfl_xor(ro3, 2);
        if (rh == 0 && cl == 4) {
            float4 o4 = {ro0 * 0.5f, ro1 * 0.5f, ro2 * 0.5f, ro3 * 0.5f};
            *(float4*)(out_read + ((size_t)b * NCC + c) * 64 + d0) = o4;
        }
    }
    __syncthreads();   // B6

    // ================= P7: feats record (130 values) =================
    if (t < 132) {
        float v = 0.f;
        if (t < 64)        v = (s_scr[t] + s_scr[64 + t]) * (1.f / 64.f);
        else if (t < 128)  v = (s_scr[64 + t] + s_scr[128 + t]) * (1.f / 64.f);
        else if (t == 128) v = (s_wsum[0] + s_wsum[1] + s_wsum[2] + s_wsum[3]
                              + s_wsum[4] + s_wsum[5] + s_wsum[6] + s_wsum[7]) * (1.f / 4096.f);
        else if (t == 129) v = s_dsum * (1.f / 64.f);
        wsf[(size_t)bc * 132 + t] = v;
    }
}

// ---------------------------------------------------------------------------
// Kernel 2: per-cell modulation MLP (distinct weights per cell)
// ---------------------------------------------------------------------------
__global__ __launch_bounds__(256, 2)
void mg_mod_kernel(
    const float* __restrict__ wsf,   const float* __restrict__ modw1,
    const float* __restrict__ modb1, const float* __restrict__ modw2,
    const float* __restrict__ modb2, const float* __restrict__ ctxp,
    const float* __restrict__ bglp,  float* __restrict__ out_ctx,
    float* __restrict__ out_bg)
{
    const int c = blockIdx.x;
    const int t = threadIdx.x;
    __shared__ float s_f[8][MODIN];
    __shared__ float s_h2[8][HMODL];

    for (int k = t; k < 8 * MODIN; k += 256) {
        const int b = k / MODIN, f = k - b * MODIN;
        float v;
        if (f < 130)      v = wsf[((size_t)b * NCC + c) * 132 + f];
        else if (f < 194) v = ctxp[((size_t)b * NCC + c) * 64 + (f - 130)];
        else              v = bglp[((size_t)b * NCC + c) * 4 + (f - 194)];
        s_f[b][f] = v;
    }
    __syncthreads();

    {
        const int hh = t & 127, bh = (t >> 7) * 4;
        float a0 = 0.f, a1 = 0.f, a2 = 0.f, a3 = 0.f;
        const float* wp = modw1 + (size_t)c * MODIN * HMODL + hh;
        for (int f = 0; f < MODIN; f++) {
            const float wv = wp[(size_t)f * HMODL];
            a0 = fmaf(s_f[bh + 0][f], wv, a0);
            a1 = fmaf(s_f[bh + 1][f], wv, a1);
            a2 = fmaf(s_f[bh + 2][f], wv, a2);
            a3 = fmaf(s_f[bh + 3][f], wv, a3);
        }
        const float bv = modb1[(size_t)c * HMODL + hh];
        s_h2[bh + 0][hh] = fast_tanh(a0 + bv);
        s_h2[bh + 1][hh] = fast_tanh(a1 + bv);
        s_h2[bh + 2][hh] = fast_tanh(a2 + bv);
        s_h2[bh + 3][hh] = fast_tanh(a3 + bv);
    }
    __syncthreads();

    for (int idx = t; idx < 8 * MODOUT; idx += 256) {
        const int b = idx / MODOUT, o = idx - b * MODOUT;
        float acc = modb2[(size_t)c * MODOUT + o];
        const float* wp = modw2 + (size_t)c * HMODL * MODOUT + o;
        const float* hrow = s_h2[b];
        for (int hh = 0; hh < HMODL; hh++)
            acc = fmaf(hrow[hh], wp[(size_t)hh * MODOUT], acc);
        if (o < 64)
            out_ctx[((size_t)b * NCC + c) * 64 + o] =
                ctxp[((size_t)b * NCC + c) * 64 + o] + acc;
        else
            out_bg[((size_t)b * NCC + c) * 4 + (o - 64)] =
                bglp[((size_t)b * NCC + c) * 4 + (o - 64)] + acc;
    }
}

extern "C" void kernel_launch(void* const* d_in, const int* in_sizes, int n_in,
                              void* d_out, int out_size, void* d_ws, size_t ws_size,
                              hipStream_t stream) {
    const float* xp     = (const float*)d_in[0];
    const float* hp     = (const float*)d_in[1];
    const float* msgp   = (const float*)d_in[2];
    const float* Wp     = (const float*)d_in[3];
    const float* decayp = (const float*)d_in[4];
    const float* ctxp   = (const float*)d_in[5];
    const float* bglp   = (const float*)d_in[6];
    const float* nidp   = (const float*)d_in[7];
    const float* sw1    = (const float*)d_in[8];
    const float* sb1    = (const float*)d_in[9];
    const float* sgs1   = (const float*)d_in[10];
    const float* sgb1   = (const float*)d_in[11];
    const float* sw2    = (const float*)d_in[12];
    const float* sb2    = (const float*)d_in[13];
    const float* sgs2   = (const float*)d_in[14];
    const float* sgb2   = (const float*)d_in[15];
    const float* mw1    = (const float*)d_in[16];
    const float* mb1    = (const float*)d_in[17];
    const float* mgs1   = (const float*)d_in[18];
    const float* mgb1   = (const float*)d_in[19];
    const float* mw2    = (const float*)d_in[20];
    const float* mb2    = (const float*)d_in[21];
    const float* mgs2   = (const float*)d_in[22];
    const float* mgb2   = (const float*)d_in[23];
    const float* iw     = (const float*)d_in[24];
    const float* ibias  = (const float*)d_in[25];
    const float* modw1  = (const float*)d_in[26];
    const float* modb1  = (const float*)d_in[27];
    const float* modw2  = (const float*)d_in[28];
    const float* modb2  = (const float*)d_in[29];
    const int*   c2g    = (const int*)d_in[30];

    float* out      = (float*)d_out;
    float* out_read = out;                 // 524288
    float* out_h    = out_read + 524288;   // 33554432
    float* out_msg  = out_h + 33554432;    // 33554432
    float* out_ctx  = out_msg + 33554432;  // 524288
    float* out_bg   = out_ctx + 524288;    // 32768

    ushort_t* wb  = (ushort_t*)d_ws;                          // 160KB bf16 weights
    float*    wsf = (float*)((char*)d_ws + FEATS_BYTE_OFF);   // 8192 x 132 f32

    mg_cvtw<<<320, 256, 0, stream>>>(sw1, sw2, mw1, mw2, wb);

    // inject -> head of each out_h tile (read by P1, overwritten by state epilogue)
    mg_inject<<<1024, 256, 0, stream>>>(xp, iw, ibias, c2g, out_h);

    mg_cell_kernel<<<8192, 512, 0, stream>>>(
        hp, msgp, Wp, decayp, bglp, nidp,
        sb1, sgs1, sgb1, sb2, sgs2, sgb2,
        mb1, mgs1, mgb1, mb2, mgs2, mgb2,
        c2g, wb, out_read, out_h, out_msg, wsf);

    mg_mod_kernel<<<1024, 256, 0, stream>>>(
        wsf, modw1, modb1, modw2, modb2, ctxp, bglp, out_ctx, out_bg);
}